// Round 5
// baseline (226.445 us; speedup 1.0000x reference)
//
#include <hip/hip_runtime.h>
#include <math.h>

#define Bb    8
#define Tseq  2048
#define Cch   512
#define Mrows 16384
#define Nqkv  1536

typedef __bf16 bf16x8 __attribute__((ext_vector_type(8)));
typedef __bf16 bf16x4 __attribute__((ext_vector_type(4)));
typedef float  f32x4  __attribute__((ext_vector_type(4)));

__device__ __forceinline__ void gld_lds16(const void* g, void* l) {
  __builtin_amdgcn_global_load_lds(
      (const __attribute__((address_space(1))) unsigned int*)g,
      (__attribute__((address_space(3))) unsigned int*)l, 16, 0, 0);
}

// LDS bank-conflict-killing XOR swizzle (verified: SQ_LDS_BANK_CONFLICT -> 0).
#define SWZ(r, g) (((r) << 6) + ((((g) ^ ((r) & 7))) << 3))
#define MFMA(d, a, b) d = __builtin_amdgcn_mfma_f32_16x16x32_bf16(a, b, d, 0, 0, 0)

// ---------------------------------------------------------------------------
// Round 11: faithful per-phase pipeline (T3+T4+T5 as a unit, not a graft).
// BM=256 x BN=128, BK=64, 512 thr (8 waves, 4Mx2N). 3 LDS slots (144 KB).
// During K-tile t, stage K-tile t+2 interleaved inside the 4 phases; the
// end-of-tile wait is vmcnt(6) (retires exactly t+1's 6 loads) - never 0
// mid-loop. Each phase: 6 ds_read_b128 (one MFMA quadrant) + 2 gld_lds +
// barrier + setprio-wrapped 8 MFMA + barrier.
// Ledger: end of t outstanding = L(t+1) u L(t+2) = 12 -> vmcnt(6).
// WAR: slot (t+2)%3 last read in t-1, separated by t's boundary barrier.
// ---------------------------------------------------------------------------

// ---------------------------------------------------------------------------
// Fused QKV-projection + Wp-precompute GEMM.
// Blocks [0,768): qkv = xb @ Wqkv_t^T + bias, 256x128 tiles over [16384][1536]
// Blocks [768,800): Wp[z] = Wc[z]-major @ Wo^T -> Wp_bt [512][2048]
// ---------------------------------------------------------------------------
__global__ __launch_bounds__(512, 1) void gemm_qkv_wp_kernel(
    const __bf16* __restrict__ xb, const __bf16* __restrict__ Wqkv_t,
    const float* __restrict__ bq, const float* __restrict__ bk,
    const float* __restrict__ bv, __bf16* __restrict__ qkv,
    const __bf16* __restrict__ Wc_t, const __bf16* __restrict__ Wob,
    __bf16* __restrict__ Wp_bt) {
  __shared__ __align__(16) __bf16 As[3][256 * 64];  // 96 KB
  __shared__ __align__(16) __bf16 Bs[3][128 * 64];  // 48 KB
  const int tid = threadIdx.x;
  const int w = tid >> 6, lane = tid & 63;
  const int wm = w & 3, wn = w >> 2;
  const int lm = lane & 15, quad = lane >> 4;
  const int srow = lane >> 3;
  const int scol = (((lane & 7) ^ srow) << 3);
  const int lid = blockIdx.x;

  const __bf16 *Ap, *Bp;
  __bf16* op;
  int lda, ldo, m0, n0;
  bool dobias;
  if (lid < 768) {
    const int xcd = lid & 7, chunk = lid >> 3;
    const int idx = xcd * 96 + chunk;
    const int mt = idx / 12, nt = idx - mt * 12;
    m0 = mt * 256; n0 = nt * 128;
    Ap = xb; lda = 512; Bp = Wqkv_t;
    op = qkv; ldo = 1536; dobias = true;
  } else {
    const int l2 = lid - 768;
    const int z = l2 >> 3, rest = l2 & 7;
    m0 = (rest >> 2) * 256; n0 = (rest & 3) * 128;
    Ap = Wc_t + z * 512; lda = 2048; Bp = Wob;
    op = Wp_bt + z * 512; ldo = 2048; dobias = false;
  }

  auto stageA = [&](int buf, int t, int it0) {
    const int k0 = t * 64;
#pragma unroll
    for (int it = it0; it < it0 + 2; ++it) {
      const int c = w * 4 + it;  // A chunk 0..31 (8 rows each)
      gld_lds16(Ap + (size_t)(m0 + c * 8 + srow) * lda + k0 + scol,
                &As[buf][c * 512]);
    }
  };
  auto stageB = [&](int buf, int t) {
    const int k0 = t * 64;
#pragma unroll
    for (int it = 0; it < 2; ++it) {
      const int c = w * 2 + it;  // B chunk 0..15
      gld_lds16(Bp + (size_t)(n0 + c * 8 + srow) * 512 + k0 + scol,
                &Bs[buf][c * 512]);
    }
  };

  f32x4 acc[4][4] = {};
  stageA(0, 0, 0); stageA(0, 0, 2); stageB(0, 0);
  stageA(1, 1, 0); stageA(1, 1, 2); stageB(1, 1);
  asm volatile("s_waitcnt vmcnt(6)" ::: "memory");
  __builtin_amdgcn_s_barrier();

  const int NT = 8;
  int st = 0;
  for (int t = 0; t < NT; ++t) {
    int sn = st + 2; if (sn >= 3) sn -= 3;
    const bool pf = (t + 2 < NT);
    // ---- phase 0: ks=0 quadrant j=0,1 ----
    bf16x8 a0[4], b0, b1;
#pragma unroll
    for (int i = 0; i < 4; ++i)
      a0[i] = *(const bf16x8*)&As[st][SWZ(wm * 64 + i * 16 + lm, quad)];
    b0 = *(const bf16x8*)&Bs[st][SWZ(wn * 64 + 0 * 16 + lm, quad)];
    b1 = *(const bf16x8*)&Bs[st][SWZ(wn * 64 + 1 * 16 + lm, quad)];
    if (pf) stageA(sn, t + 2, 0);
    __builtin_amdgcn_s_barrier();
    __builtin_amdgcn_s_setprio(1);
#pragma unroll
    for (int i = 0; i < 4; ++i) { MFMA(acc[i][0], a0[i], b0); MFMA(acc[i][1], a0[i], b1); }
    __builtin_amdgcn_s_setprio(0);
    __builtin_amdgcn_s_barrier();
    // ---- phase 1: ks=0 quadrant j=2,3 ----
    {
      bf16x8 b2 = *(const bf16x8*)&Bs[st][SWZ(wn * 64 + 2 * 16 + lm, quad)];
      bf16x8 b3 = *(const bf16x8*)&Bs[st][SWZ(wn * 64 + 3 * 16 + lm, quad)];
      if (pf) stageA(sn, t + 2, 2);
      __builtin_amdgcn_s_barrier();
      __builtin_amdgcn_s_setprio(1);
#pragma unroll
      for (int i = 0; i < 4; ++i) { MFMA(acc[i][2], a0[i], b2); MFMA(acc[i][3], a0[i], b3); }
      __builtin_amdgcn_s_setprio(0);
      __builtin_amdgcn_s_barrier();
    }
    // ---- phase 2: ks=1 quadrant j=0,1 ----
    bf16x8 a1[4], c0, c1;
#pragma unroll
    for (int i = 0; i < 4; ++i)
      a1[i] = *(const bf16x8*)&As[st][SWZ(wm * 64 + i * 16 + lm, 4 + quad)];
    c0 = *(const bf16x8*)&Bs[st][SWZ(wn * 64 + 0 * 16 + lm, 4 + quad)];
    c1 = *(const bf16x8*)&Bs[st][SWZ(wn * 64 + 1 * 16 + lm, 4 + quad)];
    if (pf) stageB(sn, t + 2);
    __builtin_amdgcn_s_barrier();
    __builtin_amdgcn_s_setprio(1);
#pragma unroll
    for (int i = 0; i < 4; ++i) { MFMA(acc[i][0], a1[i], c0); MFMA(acc[i][1], a1[i], c1); }
    __builtin_amdgcn_s_setprio(0);
    __builtin_amdgcn_s_barrier();
    // ---- phase 3: ks=1 quadrant j=2,3 ----
    {
      bf16x8 c2 = *(const bf16x8*)&Bs[st][SWZ(wn * 64 + 2 * 16 + lm, 4 + quad)];
      bf16x8 c3 = *(const bf16x8*)&Bs[st][SWZ(wn * 64 + 3 * 16 + lm, 4 + quad)];
      __builtin_amdgcn_s_setprio(1);
#pragma unroll
      for (int i = 0; i < 4; ++i) { MFMA(acc[i][2], a1[i], c2); MFMA(acc[i][3], a1[i], c3); }
      __builtin_amdgcn_s_setprio(0);
    }
    // ---- K-tile boundary ----
    if (t < NT - 2)       asm volatile("s_waitcnt vmcnt(6)" ::: "memory");
    else if (t == NT - 2) asm volatile("s_waitcnt vmcnt(0)" ::: "memory");
    if (t < NT - 1) __builtin_amdgcn_s_barrier();
    ++st; if (st == 3) st = 0;
  }
#pragma unroll
  for (int j = 0; j < 4; ++j) {
    const int col = n0 + wn * 64 + j * 16 + lm;
    float bias = 0.f;
    if (dobias) {
      const int s = col >> 9;
      const float* bp = (s == 0) ? bq : (s == 1 ? bk : bv);
      bias = bp[col & 511];
    }
#pragma unroll
    for (int i = 0; i < 4; ++i) {
      const int row0 = m0 + wm * 64 + i * 16 + quad * 4;
#pragma unroll
      for (int r = 0; r < 4; ++r)
        op[(size_t)(row0 + r) * ldo + col] = (__bf16)(acc[i][j][r] + bias);
    }
  }
}

// ---------------------------------------------------------------------------
// Conv (Wo folded): K=2048 GEMM on cat with row gather. Same phase template.
// Grid 4x64 = 256 blocks = exactly 1 block/CU.
// Epilogue: per-tap bias suffix from bj[4][512], relu, +x (fp32), leaky_relu.
// ---------------------------------------------------------------------------
__global__ __launch_bounds__(512, 1) void conv_gemm_kernel(
    const __bf16* __restrict__ A,   // catb [16384][512]
    const __bf16* __restrict__ Bt,  // Wp_bt [512][2048]
    const float* __restrict__ bc, const float* __restrict__ bj,  // bj[4][512]
    const float* __restrict__ x, float* __restrict__ out,
    const __bf16* __restrict__ zeros) {
  __shared__ __align__(16) __bf16 As[3][256 * 64];  // 96 KB
  __shared__ __align__(16) __bf16 Bs[3][128 * 64];  // 48 KB
  const int tid = threadIdx.x;
  const int w = tid >> 6, lane = tid & 63;
  const int wm = w & 3, wn = w >> 2;
  const int lm = lane & 15, quad = lane >> 4;
  const int srow = lane >> 3;
  const int scol = (((lane & 7) ^ srow) << 3);
  const int lid = blockIdx.y * 4 + blockIdx.x;
  const int xcd = lid & 7, chunk = lid >> 3;
  const int idx = xcd * 32 + chunk;
  const int mt = idx >> 2, nt = idx & 3;
  const int m0 = mt * 256, n0 = nt * 128;

  auto stageA = [&](int buf, int t, int it0) {
    const int k0 = t * 64;
    const int jtap = k0 >> 9;
    const int shift = 4 * jtap - 12;
    const int cin0 = k0 & 511;
#pragma unroll
    for (int it = it0; it < it0 + 2; ++it) {
      const int c = w * 4 + it;
      const int m = m0 + c * 8 + srow;
      const __bf16* src = (((m & (Tseq - 1)) + shift) >= 0)
                              ? A + (size_t)(m + shift) * Cch + cin0 + scol
                              : zeros + scol;
      gld_lds16(src, &As[buf][c * 512]);
    }
  };
  auto stageB = [&](int buf, int t) {
    const int k0 = t * 64;
#pragma unroll
    for (int it = 0; it < 2; ++it) {
      const int c = w * 2 + it;
      gld_lds16(Bt + (size_t)(n0 + c * 8 + srow) * 2048 + k0 + scol,
                &Bs[buf][c * 512]);
    }
  };

  f32x4 acc[4][4] = {};
  stageA(0, 0, 0); stageA(0, 0, 2); stageB(0, 0);
  stageA(1, 1, 0); stageA(1, 1, 2); stageB(1, 1);
  asm volatile("s_waitcnt vmcnt(6)" ::: "memory");
  __builtin_amdgcn_s_barrier();

  const int NT = 32;
  int st = 0;
  for (int t = 0; t < NT; ++t) {
    int sn = st + 2; if (sn >= 3) sn -= 3;
    const bool pf = (t + 2 < NT);
    // ---- phase 0 ----
    bf16x8 a0[4], b0, b1;
#pragma unroll
    for (int i = 0; i < 4; ++i)
      a0[i] = *(const bf16x8*)&As[st][SWZ(wm * 64 + i * 16 + lm, quad)];
    b0 = *(const bf16x8*)&Bs[st][SWZ(wn * 64 + 0 * 16 + lm, quad)];
    b1 = *(const bf16x8*)&Bs[st][SWZ(wn * 64 + 1 * 16 + lm, quad)];
    if (pf) stageA(sn, t + 2, 0);
    __builtin_amdgcn_s_barrier();
    __builtin_amdgcn_s_setprio(1);
#pragma unroll
    for (int i = 0; i < 4; ++i) { MFMA(acc[i][0], a0[i], b0); MFMA(acc[i][1], a0[i], b1); }
    __builtin_amdgcn_s_setprio(0);
    __builtin_amdgcn_s_barrier();
    // ---- phase 1 ----
    {
      bf16x8 b2 = *(const bf16x8*)&Bs[st][SWZ(wn * 64 + 2 * 16 + lm, quad)];
      bf16x8 b3 = *(const bf16x8*)&Bs[st][SWZ(wn * 64 + 3 * 16 + lm, quad)];
      if (pf) stageA(sn, t + 2, 2);
      __builtin_amdgcn_s_barrier();
      __builtin_amdgcn_s_setprio(1);
#pragma unroll
      for (int i = 0; i < 4; ++i) { MFMA(acc[i][2], a0[i], b2); MFMA(acc[i][3], a0[i], b3); }
      __builtin_amdgcn_s_setprio(0);
      __builtin_amdgcn_s_barrier();
    }
    // ---- phase 2 ----
    bf16x8 a1[4], c0, c1;
#pragma unroll
    for (int i = 0; i < 4; ++i)
      a1[i] = *(const bf16x8*)&As[st][SWZ(wm * 64 + i * 16 + lm, 4 + quad)];
    c0 = *(const bf16x8*)&Bs[st][SWZ(wn * 64 + 0 * 16 + lm, 4 + quad)];
    c1 = *(const bf16x8*)&Bs[st][SWZ(wn * 64 + 1 * 16 + lm, 4 + quad)];
    if (pf) stageB(sn, t + 2);
    __builtin_amdgcn_s_barrier();
    __builtin_amdgcn_s_setprio(1);
#pragma unroll
    for (int i = 0; i < 4; ++i) { MFMA(acc[i][0], a1[i], c0); MFMA(acc[i][1], a1[i], c1); }
    __builtin_amdgcn_s_setprio(0);
    __builtin_amdgcn_s_barrier();
    // ---- phase 3 ----
    {
      bf16x8 c2 = *(const bf16x8*)&Bs[st][SWZ(wn * 64 + 2 * 16 + lm, 4 + quad)];
      bf16x8 c3 = *(const bf16x8*)&Bs[st][SWZ(wn * 64 + 3 * 16 + lm, 4 + quad)];
      __builtin_amdgcn_s_setprio(1);
#pragma unroll
      for (int i = 0; i < 4; ++i) { MFMA(acc[i][2], a1[i], c2); MFMA(acc[i][3], a1[i], c3); }
      __builtin_amdgcn_s_setprio(0);
    }
    // ---- K-tile boundary ----
    if (t < NT - 2)       asm volatile("s_waitcnt vmcnt(6)" ::: "memory");
    else if (t == NT - 2) asm volatile("s_waitcnt vmcnt(0)" ::: "memory");
    if (t < NT - 1) __builtin_amdgcn_s_barrier();
    ++st; if (st == 3) st = 0;
  }
#pragma unroll
  for (int j = 0; j < 4; ++j) {
    const int col = n0 + wn * 64 + j * 16 + lm;
    const float bcv = bc[col];
    float suf[4];
    suf[3] = bj[3 * 512 + col];
    suf[2] = suf[3] + bj[2 * 512 + col];
    suf[1] = suf[2] + bj[1 * 512 + col];
    suf[0] = suf[1] + bj[0 * 512 + col];
#pragma unroll
    for (int i = 0; i < 4; ++i) {
      const int row0 = m0 + wm * 64 + i * 16 + quad * 4;
#pragma unroll
      for (int r = 0; r < 4; ++r) {
        const int row = row0 + r;
        const int tl = row & (Tseq - 1);
        int jm = 15 - tl;
        jm = (jm < 0) ? 0 : (jm >> 2);
        float v = acc[i][j][r] + bcv + suf[jm];
        v = fmaxf(v, 0.f);
        v += x[(size_t)row * Cch + col];
        out[(size_t)row * Cch + col] = (v >= 0.f) ? v : 0.2f * v;
      }
    }
  }
}

// ---------------------------------------------------------------------------
// Banded attention, LDS-staged (unchanged).
// ---------------------------------------------------------------------------
__global__ __launch_bounds__(256) void attn_band_kernel(
    const __bf16* __restrict__ qkv, __bf16* __restrict__ cat) {
  __shared__ __align__(16) __bf16 ks[70 * 128];
  __shared__ __align__(16) __bf16 vs[70 * 128];
  const int tid = threadIdx.x;
  const int bh = blockIdx.y;
  const int b = bh >> 2, h = bh & 3;
  const int t0 = blockIdx.x * 64;
  for (int c = tid; c < 70 * 16; c += 256) {
    const int row = c >> 4, chunk = c & 15;
    int s = t0 - 3 + row;
    s = (s < 0) ? 0 : ((s > Tseq - 1) ? Tseq - 1 : s);
    const __bf16* src = qkv + ((size_t)(b * Tseq + s)) * Nqkv + 512 + h * 128 + chunk * 8;
    *(bf16x8*)&ks[row * 128 + chunk * 8] = *(const bf16x8*)src;
    *(bf16x8*)&vs[row * 128 + chunk * 8] = *(const bf16x8*)(src + 512);
  }
  __syncthreads();
  const int g = tid & 15, grp = tid >> 4;
  const int d0 = g * 8;
  const float scale = 0.08838834764831845f;  // 1/sqrt(128)
#pragma unroll
  for (int tt = 0; tt < 4; ++tt) {
    const int tl = grp * 4 + tt;
    const int t = t0 + tl;
    bf16x8 qv = *(const bf16x8*)(qkv + ((size_t)(b * Tseq + t)) * Nqkv + h * 128 + d0);
    float score[7];
#pragma unroll
    for (int i = 0; i < 7; ++i) {
      const int s = t - 3 + i;
      const bool valid = (s >= 0) && (s < Tseq);
      bf16x8 kv = *(const bf16x8*)&ks[(tl + i) * 128 + d0];
      float p = 0.f;
#pragma unroll
      for (int e = 0; e < 8; ++e) p += (float)qv[e] * (float)kv[e];
      p += __shfl_xor(p, 1);
      p += __shfl_xor(p, 2);
      p += __shfl_xor(p, 4);
      p += __shfl_xor(p, 8);
      score[i] = valid ? p * scale : -1e30f;
    }
    float mx = score[0];
#pragma unroll
    for (int i = 1; i < 7; ++i) mx = fmaxf(mx, score[i]);
    float wgt[7], denom = 0.f;
#pragma unroll
    for (int i = 0; i < 7; ++i) {
      wgt[i] = (score[i] > -1e29f) ? expf(score[i] - mx) : 0.f;
      denom += wgt[i];
    }
    const float inv = 1.f / denom;
    float o[8] = {};
#pragma unroll
    for (int i = 0; i < 7; ++i) {
      bf16x8 vv = *(const bf16x8*)&vs[(tl + i) * 128 + d0];
#pragma unroll
      for (int e = 0; e < 8; ++e) o[e] += wgt[i] * (float)vv[e];
    }
    bf16x8 ov;
#pragma unroll
    for (int e = 0; e < 8; ++e) ov[e] = (__bf16)(o[e] * inv);
    *(bf16x8*)(cat + ((size_t)(b * Tseq + t)) * Cch + h * 128 + d0) = ov;
  }
}

// ---------------------------------------------------------------------------
// ONE prep kernel (flat grid) — unchanged.
// ---------------------------------------------------------------------------
#define PREP_A 8192
#define PREP_B 8960
#define PREP_C 9984
#define PREP_D 10240
#define PREP_E 10241
#define PREP_N 10273

__global__ __launch_bounds__(256) void prep_kernel(
    const float* __restrict__ x, const float* __restrict__ Wq,
    const float* __restrict__ Wk, const float* __restrict__ Wv,
    const float* __restrict__ Wo, const float* __restrict__ Wc,
    const float* __restrict__ bo,
    __bf16* __restrict__ xb, __bf16* __restrict__ Wqkv_t,
    __bf16* __restrict__ Wc_t, __bf16* __restrict__ Wob,
    float* __restrict__ bj, __bf16* __restrict__ zeros) {
  __shared__ float sArr[32][33];
  __shared__ float red[256];
  const int bid = blockIdx.x;
  const int tid = threadIdx.x;
  if (bid < PREP_A) {
    const size_t i = ((size_t)bid * 256 + tid) * 4;
    float4 v = *(const float4*)(x + i);
    bf16x4 o;
    o[0] = (__bf16)v.x; o[1] = (__bf16)v.y; o[2] = (__bf16)v.z; o[3] = (__bf16)v.w;
    *(bf16x4*)(xb + i) = o;
  } else if (bid < PREP_B) {
    const int l = bid - PREP_A;
    const int bx = l & 3, by = (l >> 2) & 15, z = l >> 6;
    const int sgrp = z >> 2, h = z & 3;
    const float* src = ((sgrp == 0) ? Wq : (sgrp == 1) ? Wk : Wv) + h * (512 * 128);
    __bf16* dst = Wqkv_t + (size_t)z * 128 * 512;
    const int tx = tid & 31, ty = tid >> 5;
    const int c0 = bx * 32, r0 = by * 32;
#pragma unroll
    for (int rr = 0; rr < 4; ++rr)
      sArr[ty + rr * 8][tx] = src[(size_t)(r0 + ty + rr * 8) * 128 + c0 + tx];
    __syncthreads();
#pragma unroll
    for (int rr = 0; rr < 4; ++rr)
      dst[(size_t)(c0 + ty + rr * 8) * 512 + r0 + tx] = (__bf16)sArr[tx][ty + rr * 8];
  } else if (bid < PREP_C) {
    const int l = bid - PREP_B;
    const int bx = l & 15, by = l >> 4;
    const int tx = tid & 31, ty = tid >> 5;
    const int c0 = bx * 32, r0 = by * 32;
#pragma unroll
    for (int rr = 0; rr < 4; ++rr)
      sArr[ty + rr * 8][tx] = Wc[(size_t)(r0 + ty + rr * 8) * 512 + c0 + tx];
    __syncthreads();
#pragma unroll
    for (int rr = 0; rr < 4; ++rr)
      Wc_t[(size_t)(c0 + ty + rr * 8) * 2048 + r0 + tx] = (__bf16)sArr[tx][ty + rr * 8];
  } else if (bid < PREP_D) {
    const int l = bid - PREP_C;
    const size_t i = ((size_t)l * 256 + tid) * 4;
    float4 v = *(const float4*)(Wo + i);
    bf16x4 o;
    o[0] = (__bf16)v.x; o[1] = (__bf16)v.y; o[2] = (__bf16)v.z; o[3] = (__bf16)v.w;
    *(bf16x4*)(Wob + i) = o;
  } else if (bid < PREP_E) {
    bf16x8 zero = {};
    *(bf16x8*)(zeros + tid * 8) = zero;
  } else {
    const int l = bid - PREP_E;
    const int j = l >> 3, nb = l & 7;
    const int n = nb * 64 + (tid & 63);
    const int cig = tid >> 6;
    const float* base = Wc + ((size_t)j * 512 + cig * 128) * 512 + n;
    float acc = 0.f;
#pragma unroll 8
    for (int ci = 0; ci < 128; ++ci) acc += bo[cig * 128 + ci] * base[(size_t)ci * 512];
    red[tid] = acc;
    __syncthreads();
    if (tid < 64)
      bj[j * 512 + n] = red[tid] + red[tid + 64] + red[tid + 128] + red[tid + 192];
  }
}

// ---------------------------------------------------------------------------
extern "C" void kernel_launch(void* const* d_in, const int* in_sizes, int n_in,
                              void* d_out, int out_size, void* d_ws, size_t ws_size,
                              hipStream_t stream) {
  const float* x  = (const float*)d_in[0];
  const float* Wq = (const float*)d_in[1];
  const float* bq = (const float*)d_in[2];
  const float* Wk = (const float*)d_in[3];
  const float* bk = (const float*)d_in[4];
  const float* Wv = (const float*)d_in[5];
  const float* bv = (const float*)d_in[6];
  const float* Wo = (const float*)d_in[7];
  const float* bo = (const float*)d_in[8];
  const float* Wc = (const float*)d_in[9];
  const float* bc = (const float*)d_in[10];
  float* out = (float*)d_out;

  char* p = (char*)d_ws;
  __bf16* xb     = (__bf16*)p;  p += (size_t)Mrows * Cch * 2;    // 16 MiB
  __bf16* qkv    = (__bf16*)p;  p += (size_t)Mrows * Nqkv * 2;   // 48 MiB
  __bf16* catb   = (__bf16*)p;  p += (size_t)Mrows * Cch * 2;    // 16 MiB
  __bf16* Wqkv_t = (__bf16*)p;  p += (size_t)Nqkv * Cch * 2;     // 1.5 MiB
  __bf16* Wc_t   = (__bf16*)p;  p += (size_t)Cch * 2048 * 2;     // 2 MiB
  __bf16* Wob    = (__bf16*)p;  p += (size_t)Cch * Cch * 2;      // 0.5 MiB
  __bf16* Wp_bt  = (__bf16*)p;  p += (size_t)Cch * 2048 * 2;     // 2 MiB
  float*  bj     = (float*)p;   p += 4 * Cch * 4;                // 8 KiB
  __bf16* zeros  = (__bf16*)p;  p += 4096;

  prep_kernel<<<PREP_N, 256, 0, stream>>>(x, Wq, Wk, Wv, Wo, Wc, bo,
                                          xb, Wqkv_t, Wc_t, Wob, bj, zeros);

  gemm_qkv_wp_kernel<<<800, 512, 0, stream>>>(xb, Wqkv_t, bq, bk, bv, qkv,
                                              Wc_t, Wob, Wp_bt);

  attn_band_kernel<<<dim3(Tseq / 64, Bb * 4), 256, 0, stream>>>(qkv, catb);

  conv_gemm_kernel<<<dim3(Cch / 128, Mrows / 128 / 2), 512, 0, stream>>>(
      catb, Wp_bt, bc, bj, x, out, zeros);
}

// Round 6
// 210.488 us; speedup vs baseline: 1.0758x; 1.0758x over previous
//
#include <hip/hip_runtime.h>
#include <math.h>

#define Bb    8
#define Tseq  2048
#define Cch   512
#define Mrows 16384
#define Nqkv  1536

typedef __bf16 bf16x8 __attribute__((ext_vector_type(8)));
typedef __bf16 bf16x4 __attribute__((ext_vector_type(4)));
typedef float  f32x4  __attribute__((ext_vector_type(4)));

__device__ __forceinline__ void gld_lds16(const void* g, void* l) {
  __builtin_amdgcn_global_load_lds(
      (const __attribute__((address_space(1))) unsigned int*)g,
      (__attribute__((address_space(3))) unsigned int*)l, 16, 0, 0);
}

// LDS bank-conflict-killing XOR swizzle: row r's 8-element group g lives at
// group (g ^ (r&7)). Verified round 6: SQ_LDS_BANK_CONFLICT 1.26e7 -> 0.
#define SWZ(r, g) (((r) << 6) + ((((g) ^ ((r) & 7))) << 3))

// ---------------------------------------------------------------------------
// Round 12: full revert to the round-0 structure (all schedule variants
// R1/R3/R4/R5 regressed 52-64us vs 49.7us — coarse counted-vmcnt grafts and
// per-phase ports both lose here; small K-loop + small MFMA clusters put this
// kernel outside the 8-phase template's regime). Single change vs round-0:
// conv tile 128x128 -> 64x128, grid 512 -> 1024 blocks = 4 blocks/CU
// (was grid-limited to 2). Cross-block wave overlap (m114) is what hides the
// barrier drain; occupancy was the binding constraint, not the schedule.
// ---------------------------------------------------------------------------

// ---------------------------------------------------------------------------
// Fused QKV-projection + Wp-precompute GEMM (exact round-0 kernel).
// Blocks [0,1536): qkv = xb @ Wqkv_t^T + bias -> [16384][1536].
// Blocks [1536,1600): Wp[z] = Wc[z]^T-major @ Wo^T -> Wp_bt [512][2048].
// ---------------------------------------------------------------------------
__global__ __launch_bounds__(256, 2) void gemm_qkv_wp_kernel(
    const __bf16* __restrict__ xb, const __bf16* __restrict__ Wqkv_t,
    const float* __restrict__ bq, const float* __restrict__ bk,
    const float* __restrict__ bv, __bf16* __restrict__ qkv,
    const __bf16* __restrict__ Wc_t, const __bf16* __restrict__ Wob,
    __bf16* __restrict__ Wp_bt) {
  __shared__ __align__(16) __bf16 As[128 * 64];
  __shared__ __align__(16) __bf16 Bs[128 * 64];
  const int tid = threadIdx.x;
  const int w = tid >> 6, lane = tid & 63;
  const int wm = w & 1, wn = w >> 1;
  const int lm = lane & 15, quad = lane >> 4;
  const int srow = lane >> 3;                   // staging row-in-chunk
  const int scol = (((lane & 7) ^ srow) << 3);  // staging swizzled col
  const int lid = blockIdx.x;

  const __bf16 *Ap, *Bp;
  __bf16* op;
  int lda, ldo, m0, n0;
  bool dobias;
  if (lid < 1536) {
    const int xcd = lid & 7, chunk = lid >> 3;
    const int idx = xcd * 192 + chunk;
    const int mt = idx / 12, nt = idx - mt * 12;
    m0 = mt * 128; n0 = nt * 128;
    Ap = xb; lda = 512; Bp = Wqkv_t;
    op = qkv; ldo = 1536; dobias = true;
  } else {
    const int l2 = lid - 1536;
    const int z = l2 >> 4;
    m0 = ((l2 >> 2) & 3) * 128; n0 = (l2 & 3) * 128;
    Ap = Wc_t + z * 512; lda = 2048; Bp = Wob;
    op = Wp_bt + z * 512; ldo = 2048; dobias = false;
  }

  f32x4 acc[4][4] = {};
  for (int k0 = 0; k0 < 512; k0 += 64) {
#pragma unroll
    for (int it = 0; it < 4; ++it) {
      const int c = w * 4 + it;
      const int row = c * 8 + srow;
      gld_lds16(Ap + (size_t)(m0 + row) * lda + k0 + scol, &As[c * 512]);
      gld_lds16(Bp + (size_t)(n0 + row) * 512 + k0 + scol, &Bs[c * 512]);
    }
    __syncthreads();
#pragma unroll
    for (int ks = 0; ks < 2; ++ks) {
      bf16x8 af[4], bfr[4];
#pragma unroll
      for (int i = 0; i < 4; ++i)
        af[i] = *(const bf16x8*)&As[SWZ(wm * 64 + i * 16 + lm, ks * 4 + quad)];
#pragma unroll
      for (int j = 0; j < 4; ++j)
        bfr[j] = *(const bf16x8*)&Bs[SWZ(wn * 64 + j * 16 + lm, ks * 4 + quad)];
#pragma unroll
      for (int i = 0; i < 4; ++i)
#pragma unroll
        for (int j = 0; j < 4; ++j)
          acc[i][j] = __builtin_amdgcn_mfma_f32_16x16x32_bf16(af[i], bfr[j], acc[i][j], 0, 0, 0);
    }
    __syncthreads();
  }
#pragma unroll
  for (int j = 0; j < 4; ++j) {
    const int col = n0 + wn * 64 + j * 16 + lm;
    float bias = 0.f;
    if (dobias) {
      const int s = col >> 9;
      const float* bp = (s == 0) ? bq : (s == 1 ? bk : bv);
      bias = bp[col & 511];
    }
#pragma unroll
    for (int i = 0; i < 4; ++i) {
      const int row0 = m0 + wm * 64 + i * 16 + quad * 4;
#pragma unroll
      for (int r = 0; r < 4; ++r)
        op[(size_t)(row0 + r) * ldo + col] = (__bf16)(acc[i][j][r] + bias);
    }
  }
}

// ---------------------------------------------------------------------------
// Conv (Wo folded): K=2048 GEMM on cat with row gather, BK=64, swizzled LDS.
// Round 12: BM=64 x BN=128, grid (4,256) = 1024 blocks = 4 blocks/CU (was 2).
// A (catb) still read exactly 4x; B (Wp_bt 2MB) re-reads are L2-resident.
// Epilogue: per-tap bias suffix from bj[4][512], relu, +x (fp32), leaky_relu.
// ---------------------------------------------------------------------------
__global__ __launch_bounds__(256, 4) void conv_gemm_kernel(
    const __bf16* __restrict__ A,   // catb [16384][512]
    const __bf16* __restrict__ Bt,  // Wp_bt [512][2048]
    const float* __restrict__ bc, const float* __restrict__ bj,  // bj[4][512]
    const float* __restrict__ x, float* __restrict__ out,
    const __bf16* __restrict__ zeros) {
  __shared__ __align__(16) __bf16 As[64 * 64];    // 8 KB
  __shared__ __align__(16) __bf16 Bs[128 * 64];   // 16 KB
  const int tid = threadIdx.x;
  const int w = tid >> 6, lane = tid & 63;
  const int wm = w & 1, wn = w >> 1;   // 2M x 2N wave grid; wave tile 32x64
  const int lm = lane & 15, quad = lane >> 4;
  const int srow = lane >> 3;
  const int scol = (((lane & 7) ^ srow) << 3);
  // XCD-aware remap over the 1024-block grid (128 contiguous tiles per XCD;
  // consecutive idx on one XCD share the same A-panel -> L2 locality).
  const int lid = blockIdx.y * 4 + blockIdx.x;
  const int xcd = lid & 7, chunk = lid >> 3;
  const int idx = xcd * 128 + chunk;
  const int mt = idx >> 2, nt = idx & 3;
  const int m0 = mt * 64, n0 = nt * 128;

  f32x4 acc[2][4] = {};
  for (int k0 = 0; k0 < 4 * Cch; k0 += 64) {
    const int jtap = k0 >> 9;
    const int shift = 4 * jtap - 12;
    const int cin0 = k0 & 511;
    // A: 8 chunks of 8 rows (64 rows), 2 loads/thread
#pragma unroll
    for (int it = 0; it < 2; ++it) {
      const int c = w * 2 + it;
      const int row = c * 8 + srow;
      const int m = m0 + row;
      const __bf16* src = (((m & (Tseq - 1)) + shift) >= 0)
                              ? A + (size_t)(m + shift) * Cch + cin0 + scol
                              : zeros + scol;
      gld_lds16(src, &As[c * 512]);
    }
    // B: 16 chunks of 8 rows (128 rows), 4 loads/thread
#pragma unroll
    for (int it = 0; it < 4; ++it) {
      const int c = w * 4 + it;
      const int row = c * 8 + srow;
      gld_lds16(Bt + (size_t)(n0 + row) * 2048 + k0 + scol, &Bs[c * 512]);
    }
    __syncthreads();
#pragma unroll
    for (int ks = 0; ks < 2; ++ks) {
      bf16x8 af[2], bfr[4];
#pragma unroll
      for (int i = 0; i < 2; ++i)
        af[i] = *(const bf16x8*)&As[SWZ(wm * 32 + i * 16 + lm, ks * 4 + quad)];
#pragma unroll
      for (int j = 0; j < 4; ++j)
        bfr[j] = *(const bf16x8*)&Bs[SWZ(wn * 64 + j * 16 + lm, ks * 4 + quad)];
#pragma unroll
      for (int i = 0; i < 2; ++i)
#pragma unroll
        for (int j = 0; j < 4; ++j)
          acc[i][j] = __builtin_amdgcn_mfma_f32_16x16x32_bf16(af[i], bfr[j], acc[i][j], 0, 0, 0);
    }
    __syncthreads();
  }
#pragma unroll
  for (int j = 0; j < 4; ++j) {
    const int col = n0 + wn * 64 + j * 16 + lm;
    const float bcv = bc[col];
    float suf[4];
    suf[3] = bj[3 * 512 + col];
    suf[2] = suf[3] + bj[2 * 512 + col];
    suf[1] = suf[2] + bj[1 * 512 + col];
    suf[0] = suf[1] + bj[0 * 512 + col];
#pragma unroll
    for (int i = 0; i < 2; ++i) {
      const int row0 = m0 + wm * 32 + i * 16 + quad * 4;
#pragma unroll
      for (int r = 0; r < 4; ++r) {
        const int row = row0 + r;
        const int tl = row & (Tseq - 1);
        int jm = 15 - tl;
        jm = (jm < 0) ? 0 : (jm >> 2);
        float v = acc[i][j][r] + bcv + suf[jm];
        v = fmaxf(v, 0.f);
        v += x[(size_t)row * Cch + col];
        out[(size_t)row * Cch + col] = (v >= 0.f) ? v : 0.2f * v;
      }
    }
  }
}

// ---------------------------------------------------------------------------
// Banded attention, LDS-staged: one block per (b,h) x 64-t strip. Stage the
// 70 k-rows and 70 v-rows the strip needs into LDS once (35 KB), then 16-lane
// groups compute 4 t's each from LDS.
// ---------------------------------------------------------------------------
__global__ __launch_bounds__(256) void attn_band_kernel(
    const __bf16* __restrict__ qkv, __bf16* __restrict__ cat) {
  __shared__ __align__(16) __bf16 ks[70 * 128];
  __shared__ __align__(16) __bf16 vs[70 * 128];
  const int tid = threadIdx.x;
  const int bh = blockIdx.y;
  const int b = bh >> 2, h = bh & 3;
  const int t0 = blockIdx.x * 64;
  for (int c = tid; c < 70 * 16; c += 256) {
    const int row = c >> 4, chunk = c & 15;
    int s = t0 - 3 + row;
    s = (s < 0) ? 0 : ((s > Tseq - 1) ? Tseq - 1 : s);
    const __bf16* src = qkv + ((size_t)(b * Tseq + s)) * Nqkv + 512 + h * 128 + chunk * 8;
    *(bf16x8*)&ks[row * 128 + chunk * 8] = *(const bf16x8*)src;
    *(bf16x8*)&vs[row * 128 + chunk * 8] = *(const bf16x8*)(src + 512);
  }
  __syncthreads();
  const int g = tid & 15, grp = tid >> 4;
  const int d0 = g * 8;
  const float scale = 0.08838834764831845f;  // 1/sqrt(128)
#pragma unroll
  for (int tt = 0; tt < 4; ++tt) {
    const int tl = grp * 4 + tt;  // local t in [0,64)
    const int t = t0 + tl;
    bf16x8 qv = *(const bf16x8*)(qkv + ((size_t)(b * Tseq + t)) * Nqkv + h * 128 + d0);
    float score[7];
#pragma unroll
    for (int i = 0; i < 7; ++i) {
      const int s = t - 3 + i;
      const bool valid = (s >= 0) && (s < Tseq);
      bf16x8 kv = *(const bf16x8*)&ks[(tl + i) * 128 + d0];
      float p = 0.f;
#pragma unroll
      for (int e = 0; e < 8; ++e) p += (float)qv[e] * (float)kv[e];
      p += __shfl_xor(p, 1);
      p += __shfl_xor(p, 2);
      p += __shfl_xor(p, 4);
      p += __shfl_xor(p, 8);
      score[i] = valid ? p * scale : -1e30f;
    }
    float mx = score[0];
#pragma unroll
    for (int i = 1; i < 7; ++i) mx = fmaxf(mx, score[i]);
    float wgt[7], denom = 0.f;
#pragma unroll
    for (int i = 0; i < 7; ++i) {
      wgt[i] = (score[i] > -1e29f) ? expf(score[i] - mx) : 0.f;
      denom += wgt[i];
    }
    const float inv = 1.f / denom;
    float o[8] = {};
#pragma unroll
    for (int i = 0; i < 7; ++i) {
      bf16x8 vv = *(const bf16x8*)&vs[(tl + i) * 128 + d0];
#pragma unroll
      for (int e = 0; e < 8; ++e) o[e] += wgt[i] * (float)vv[e];
    }
    bf16x8 ov;
#pragma unroll
    for (int e = 0; e < 8; ++e) ov[e] = (__bf16)(o[e] * inv);
    *(bf16x8*)(cat + ((size_t)(b * Tseq + t)) * Cch + h * 128 + d0) = ov;
  }
}

// ---------------------------------------------------------------------------
// ONE prep kernel (flat grid):
//  [0,8192)       cast x -> xb (bf16)
//  [8192,8960)    transpose-cast Wq/Wk/Wv -> Wqkv_t [1536][512]
//  [8960,9984)    transpose-cast Wc (2048x512) -> Wc_t [512][2048]
//  [9984,10240)   cast Wo -> Wob (row-major)
//  10240          zero-fill zeros buffer
//  [10241,10273)  bias partials bj[j][n] = sum_ci bo[ci]*Wc[j,ci,n]
// ---------------------------------------------------------------------------
#define PREP_A 8192
#define PREP_B 8960
#define PREP_C 9984
#define PREP_D 10240
#define PREP_E 10241
#define PREP_N 10273

__global__ __launch_bounds__(256) void prep_kernel(
    const float* __restrict__ x, const float* __restrict__ Wq,
    const float* __restrict__ Wk, const float* __restrict__ Wv,
    const float* __restrict__ Wo, const float* __restrict__ Wc,
    const float* __restrict__ bo,
    __bf16* __restrict__ xb, __bf16* __restrict__ Wqkv_t,
    __bf16* __restrict__ Wc_t, __bf16* __restrict__ Wob,
    float* __restrict__ bj, __bf16* __restrict__ zeros) {
  __shared__ float sArr[32][33];
  __shared__ float red[256];
  const int bid = blockIdx.x;
  const int tid = threadIdx.x;
  if (bid < PREP_A) {
    const size_t i = ((size_t)bid * 256 + tid) * 4;
    float4 v = *(const float4*)(x + i);
    bf16x4 o;
    o[0] = (__bf16)v.x; o[1] = (__bf16)v.y; o[2] = (__bf16)v.z; o[3] = (__bf16)v.w;
    *(bf16x4*)(xb + i) = o;
  } else if (bid < PREP_B) {
    const int l = bid - PREP_A;
    const int bx = l & 3, by = (l >> 2) & 15, z = l >> 6;
    const int sgrp = z >> 2, h = z & 3;
    const float* src = ((sgrp == 0) ? Wq : (sgrp == 1) ? Wk : Wv) + h * (512 * 128);
    __bf16* dst = Wqkv_t + (size_t)z * 128 * 512;
    const int tx = tid & 31, ty = tid >> 5;
    const int c0 = bx * 32, r0 = by * 32;
#pragma unroll
    for (int rr = 0; rr < 4; ++rr)
      sArr[ty + rr * 8][tx] = src[(size_t)(r0 + ty + rr * 8) * 128 + c0 + tx];
    __syncthreads();
#pragma unroll
    for (int rr = 0; rr < 4; ++rr)
      dst[(size_t)(c0 + ty + rr * 8) * 512 + r0 + tx] = (__bf16)sArr[tx][ty + rr * 8];
  } else if (bid < PREP_C) {
    const int l = bid - PREP_B;
    const int bx = l & 15, by = l >> 4;
    const int tx = tid & 31, ty = tid >> 5;
    const int c0 = bx * 32, r0 = by * 32;
#pragma unroll
    for (int rr = 0; rr < 4; ++rr)
      sArr[ty + rr * 8][tx] = Wc[(size_t)(r0 + ty + rr * 8) * 512 + c0 + tx];
    __syncthreads();
#pragma unroll
    for (int rr = 0; rr < 4; ++rr)
      Wc_t[(size_t)(c0 + ty + rr * 8) * 2048 + r0 + tx] = (__bf16)sArr[tx][ty + rr * 8];
  } else if (bid < PREP_D) {
    const int l = bid - PREP_C;
    const size_t i = ((size_t)l * 256 + tid) * 4;
    float4 v = *(const float4*)(Wo + i);
    bf16x4 o;
    o[0] = (__bf16)v.x; o[1] = (__bf16)v.y; o[2] = (__bf16)v.z; o[3] = (__bf16)v.w;
    *(bf16x4*)(Wob + i) = o;
  } else if (bid < PREP_E) {
    bf16x8 zero = {};
    *(bf16x8*)(zeros + tid * 8) = zero;
  } else {
    const int l = bid - PREP_E;
    const int j = l >> 3, nb = l & 7;
    const int n = nb * 64 + (tid & 63);
    const int cig = tid >> 6;
    const float* base = Wc + ((size_t)j * 512 + cig * 128) * 512 + n;
    float acc = 0.f;
#pragma unroll 8
    for (int ci = 0; ci < 128; ++ci) acc += bo[cig * 128 + ci] * base[(size_t)ci * 512];
    red[tid] = acc;
    __syncthreads();
    if (tid < 64)
      bj[j * 512 + n] = red[tid] + red[tid + 64] + red[tid + 128] + red[tid + 192];
  }
}

// ---------------------------------------------------------------------------
extern "C" void kernel_launch(void* const* d_in, const int* in_sizes, int n_in,
                              void* d_out, int out_size, void* d_ws, size_t ws_size,
                              hipStream_t stream) {
  const float* x  = (const float*)d_in[0];
  const float* Wq = (const float*)d_in[1];
  const float* bq = (const float*)d_in[2];
  const float* Wk = (const float*)d_in[3];
  const float* bk = (const float*)d_in[4];
  const float* Wv = (const float*)d_in[5];
  const float* bv = (const float*)d_in[6];
  const float* Wo = (const float*)d_in[7];
  const float* bo = (const float*)d_in[8];
  const float* Wc = (const float*)d_in[9];
  const float* bc = (const float*)d_in[10];
  float* out = (float*)d_out;

  char* p = (char*)d_ws;
  __bf16* xb     = (__bf16*)p;  p += (size_t)Mrows * Cch * 2;    // 16 MiB
  __bf16* qkv    = (__bf16*)p;  p += (size_t)Mrows * Nqkv * 2;   // 48 MiB
  __bf16* catb   = (__bf16*)p;  p += (size_t)Mrows * Cch * 2;    // 16 MiB
  __bf16* Wqkv_t = (__bf16*)p;  p += (size_t)Nqkv * Cch * 2;     // 1.5 MiB
  __bf16* Wc_t   = (__bf16*)p;  p += (size_t)Cch * 2048 * 2;     // 2 MiB
  __bf16* Wob    = (__bf16*)p;  p += (size_t)Cch * Cch * 2;      // 0.5 MiB
  __bf16* Wp_bt  = (__bf16*)p;  p += (size_t)Cch * 2048 * 2;     // 2 MiB
  float*  bj     = (float*)p;   p += 4 * Cch * 4;                // 8 KiB
  __bf16* zeros  = (__bf16*)p;  p += 4096;

  prep_kernel<<<PREP_N, 256, 0, stream>>>(x, Wq, Wk, Wv, Wo, Wc, bo,
                                          xb, Wqkv_t, Wc_t, Wob, bj, zeros);

  // QKV projection + Wp = Wo @ Wc[j] precompute, fused into one launch
  gemm_qkv_wp_kernel<<<1600, 256, 0, stream>>>(xb, Wqkv_t, bq, bk, bv, qkv,
                                               Wc_t, Wob, Wp_bt);

  attn_band_kernel<<<dim3(Tseq / 64, Bb * 4), 256, 0, stream>>>(qkv, catb);

  conv_gemm_kernel<<<dim3(4, 256), 256, 0, stream>>>(
      catb, Wp_bt, bc, bj, x, out, zeros);
}